// Round 1
// baseline (418.907 us; speedup 1.0000x reference)
//
#include <hip/hip_runtime.h>

// Lfm2ShortConv decode: out = (Cg ⊙ conv_out) @ W2^T
//   Cg = x @ W1[D:2D]^T          (Bg,xg branches are dead — feed a discarded cache update)
//   conv_out[b,d] = sum_l conv_cache[0,b,d,l] * conv_w[d,0,l]
// M=2048 (batch), N=K=1024. Two bf16-MFMA GEMMs, gate fused in GEMM1 epilogue.
//
// Round 3: the timed region is dominated by ~362 us of harness re-poison fills
// (2 x 1.125 GiB @ ~83% HBM peak); our kernels are the remaining ~16 us tail.
// This version shaves that tail:
//   - prep_cast eliminated: fp32->bf16 RNE (v_cvt_pk_bf16_f32) fused into the
//     GEMM staging path (traffic 72 MB -> 56 MB, 3 launches -> 2).
//   - LDS double-buffered, 2-phase prefetch: issue next-tile loads -> MFMA on
//     current buffer -> cvt+ds_write next buffer -> ONE barrier per K-step
//     (was: full vmcnt(0)+barrier drain twice per step at 1 wave/SIMD).
// Block tile 64x64, 128 threads (2 waves), wave = 64(M)x32(N) subtile.
// LDS layout unchanged (slot s of row r holds k-group s^(r&7)): every
// ds_read_b128 fragment read stays conflict-free.

#define MDIM 2048
#define NDIM 1024
#define KDIM 1024

typedef __attribute__((ext_vector_type(8))) short bf16x8;
typedef __attribute__((ext_vector_type(4))) float f32x4;

__device__ __forceinline__ unsigned short bf16rn(float f) {
    unsigned int u = __builtin_bit_cast(unsigned int, f);
    return (unsigned short)((u + 0x7FFFu + ((u >> 16) & 1u)) >> 16);
}

// packed f32->bf16 RNE, 2 elems/inst. No builtin on gfx950 (guide T12) -> asm.
__device__ __forceinline__ unsigned int cvtpk(float lo, float hi) {
    unsigned int r;
    asm("v_cvt_pk_bf16_f32 %0, %1, %2" : "=v"(r) : "v"(lo), "v"(hi));
    return r;
}

#define GLDS16(gp, lp)                                                          \
    __builtin_amdgcn_global_load_lds(                                           \
        (const __attribute__((address_space(1))) void*)(gp),                    \
        (__attribute__((address_space(3))) void*)(lp), 16, 0, 0)

// ---------------------------------------------------------------------------
// GEMM: C[M x N] = A[M x K] * B[N x K]^T, bf16 MFMA, fp32 accumulate.
// GATE=true  (GEMM1): A = x   (fp32, reg-staged + cvt), B = W1c (fp32, cvt),
//                     epilogue gates with conv cache and writes bf16 y.
// GATE=false (GEMM2): A = y   (bf16, global_load_lds), B = W2  (fp32, cvt),
//                     epilogue writes fp32 out.
// Staging map (reg-staged fp32 tiles): thread t -> row r=t>>1, k-half h=t&1;
// loads 32 floats (8 float4), writes 4 bf16x8 groups g at slot (4h+g)^(r&7)
// -> identical LDS image to the old glds layout, so fragment reads unchanged.
// ---------------------------------------------------------------------------
template <bool GATE>
__global__ __launch_bounds__(128) void gemm(
    const void* __restrict__ Aptr, const float* __restrict__ Bw,
    const float* __restrict__ cache,      // conv_cache layer 0: [M][N][3]
    const float* __restrict__ convw,      // [N][3]
    unsigned short* __restrict__ Ybf, float* __restrict__ Yout)
{
    __shared__ __align__(16) unsigned short ldsA[2][64 * 64];
    __shared__ __align__(16) unsigned short ldsB[2][64 * 64];

    const int tid  = threadIdx.x;
    const int lane = tid & 63;
    const int w    = tid >> 6;           // wave 0..1
    const int col  = lane & 15;
    const int quad = lane >> 4;
    const int m0   = blockIdx.y * 64;
    const int n0   = blockIdx.x * 64;

    // reg-staging coordinates
    const int r = tid >> 1;              // tile row 0..63
    const int h = tid & 1;               // k-half (32 floats each)

    const float4* bsrc = (const float4*)(Bw + (size_t)(n0 + r) * KDIM + h * 32);
    const float4* asrc = nullptr;
    size_t aoff[4] = {};
    if constexpr (GATE) {
        asrc = (const float4*)((const float*)Aptr + (size_t)(m0 + r) * KDIM + h * 32);
    } else {
        // glds staging: chunk c = rows [8c,8c+8); lane l writes 16B at c*1024+l*16
        // => row 8c+(l>>3), slot l&7 holds k-group (l&7)^(l>>3). Wave w: chunks 4w..4w+3.
        const int rsub = lane >> 3;
        const int kg   = (lane & 7) ^ rsub;
#pragma unroll
        for (int t = 0; t < 4; ++t) {
            const int c = 4 * w + t;
            aoff[t] = (size_t)(m0 + 8 * c + rsub) * KDIM + kg * 8;
        }
    }

    float4 a4[8], b4[8];

    auto load_tiles = [&](int k0, int buf) {
        const int kf = k0 >> 2;
        if constexpr (GATE) {
#pragma unroll
            for (int j = 0; j < 8; ++j) a4[j] = asrc[kf + j];
        } else {
#pragma unroll
            for (int t = 0; t < 4; ++t)
                GLDS16((const unsigned short*)Aptr + aoff[t] + k0,
                       &ldsA[buf][(4 * w + t) * 512]);
        }
#pragma unroll
        for (int j = 0; j < 8; ++j) b4[j] = bsrc[kf + j];
    };

    auto cvt_write = [&](int buf) {
#pragma unroll
        for (int g = 0; g < 4; ++g) {
            uint4 wv;
            wv.x = cvtpk(b4[2 * g].x, b4[2 * g].y);
            wv.y = cvtpk(b4[2 * g].z, b4[2 * g].w);
            wv.z = cvtpk(b4[2 * g + 1].x, b4[2 * g + 1].y);
            wv.w = cvtpk(b4[2 * g + 1].z, b4[2 * g + 1].w);
            const int slot = (4 * h + g) ^ (r & 7);
            *(uint4*)&ldsB[buf][r * 64 + slot * 8] = wv;
        }
        if constexpr (GATE) {
#pragma unroll
            for (int g = 0; g < 4; ++g) {
                uint4 wv;
                wv.x = cvtpk(a4[2 * g].x, a4[2 * g].y);
                wv.y = cvtpk(a4[2 * g].z, a4[2 * g].w);
                wv.z = cvtpk(a4[2 * g + 1].x, a4[2 * g + 1].y);
                wv.w = cvtpk(a4[2 * g + 1].z, a4[2 * g + 1].w);
                const int slot = (4 * h + g) ^ (r & 7);
                *(uint4*)&ldsA[buf][r * 64 + slot * 8] = wv;
            }
        }
    };

    f32x4 acc[4][2] = {};

    // prologue: stage K-tile 0 into buffer 0
    load_tiles(0, 0);
    cvt_write(0);
    __syncthreads();

    int cur = 0;
    for (int k0 = 0; k0 < KDIM; k0 += 64) {
        const bool more = (k0 + 64 < KDIM);   // block-uniform
        if (more) load_tiles(k0 + 64, cur ^ 1);   // overlap with compute below

#pragma unroll
        for (int ks = 0; ks < 2; ++ks) {
            const int slot = (ks * 4 + quad) ^ (col & 7);
            bf16x8 av[4], bv[2];
#pragma unroll
            for (int i = 0; i < 4; ++i)
                av[i] = *(const bf16x8*)&ldsA[cur][(i * 16 + col) * 64 + slot * 8];
#pragma unroll
            for (int j = 0; j < 2; ++j)
                bv[j] = *(const bf16x8*)&ldsB[cur][(w * 32 + j * 16 + col) * 64 + slot * 8];
#pragma unroll
            for (int i = 0; i < 4; ++i)
#pragma unroll
                for (int j = 0; j < 2; ++j)
                    acc[i][j] = __builtin_amdgcn_mfma_f32_16x16x32_bf16(
                        av[i], bv[j], acc[i][j], 0, 0, 0);
        }

        if (more) {
            cvt_write(cur ^ 1);   // compiler inserts vmcnt waits at first use
            __syncthreads();      // writes (incl. glds) visible; old reads done
            cur ^= 1;
        }
    }

    // Epilogue. C/D mapping (HW-verified): row = quad*4 + rr, col = lane&15.
#pragma unroll
    for (int j = 0; j < 2; ++j) {
        const int n = n0 + w * 32 + j * 16 + col;
        float cw0 = 0.f, cw1 = 0.f, cw2 = 0.f;
        if constexpr (GATE) {
            cw0 = convw[n * 3 + 0];
            cw1 = convw[n * 3 + 1];
            cw2 = convw[n * 3 + 2];
        }
#pragma unroll
        for (int i = 0; i < 4; ++i) {
#pragma unroll
            for (int rr = 0; rr < 4; ++rr) {
                const int m = m0 + i * 16 + quad * 4 + rr;
                float v = acc[i][j][rr];
                if constexpr (GATE) {
                    const float* cp = cache + ((size_t)m * NDIM + n) * 3;
                    v *= cp[0] * cw0 + cp[1] * cw1 + cp[2] * cw2;
                    Ybf[(size_t)m * NDIM + n] = bf16rn(v);
                } else {
                    Yout[(size_t)m * NDIM + n] = v;
                }
            }
        }
    }
}

// ---------------------------------------------------------------------------
extern "C" void kernel_launch(void* const* d_in, const int* in_sizes, int n_in,
                              void* d_out, int out_size, void* d_ws, size_t ws_size,
                              hipStream_t stream)
{
    const float* x     = (const float*)d_in[0];
    const float* cache = (const float*)d_in[1];   // layer 0 is at offset 0
    const float* w1    = (const float*)d_in[3];
    const float* w2    = (const float*)d_in[4];
    const float* cw    = (const float*)d_in[5];
    float* out = (float*)d_out;

    unsigned short* yb = (unsigned short*)d_ws;   // 4 MB intermediate (bf16 y)

    dim3 grid(NDIM / 64, MDIM / 64);  // 16 x 32 = 512 blocks, 128 thr each
    gemm<true><<<grid, dim3(128), 0, stream>>>(
        x, w1 + (size_t)NDIM * KDIM,  // W1 rows [D, 2D) = Cg projection
        cache, cw, yb, nullptr);
    gemm<false><<<grid, dim3(128), 0, stream>>>(
        yb, w2, nullptr, nullptr, nullptr, out);
}

// Round 2
// 392.302 us; speedup vs baseline: 1.0678x; 1.0678x over previous
//
#include <hip/hip_runtime.h>

// Lfm2ShortConv decode: out = (Cg ⊙ conv_out) @ W2^T
//   Cg = x @ W1[D:2D]^T          (Bg,xg branches are dead — feed a discarded cache update)
//   conv_out[b,d] = sum_l conv_cache[0,b,d,l] * conv_w[d,0,l]
// M=2048 (batch), N=K=1024. Two bf16-MFMA GEMMs, gate fused in GEMM1 epilogue.
//
// Round 4: timed region is ~362 us of harness re-poison fills (2 x 1.125 GiB
// @ ~83% HBM peak) + our kernels. Round-1 fusion regressed (57 us ours) because
// reg-staging used a 4KB-stride lane map: every global_load_dwordx4 touched 64
// distinct cachelines (per-instruction uncoalesced, ~8K TA requests/CU/K-step).
// This round keeps the fusion + double-buffer but fixes the map:
//   thread t -> base-row rb=(t>>3)&15, k-group cc=t&7; rows rb+16*jr (jr=0..3).
//   Per load instruction a wave covers 8 consecutive rows x 256 B contiguous
//   (same segment quality as global_load_lds). cc IS the k-group, so the
//   swizzle slot cc^(rb&7) is thread-constant; 4 ds_write_b128 at +jr*2KB.
// LDS image identical to the proven round-0 layout => fragment reads unchanged.

#define MDIM 2048
#define NDIM 1024
#define KDIM 1024

typedef __attribute__((ext_vector_type(8))) short bf16x8;
typedef __attribute__((ext_vector_type(4))) float f32x4;

__device__ __forceinline__ unsigned short bf16rn(float f) {
    unsigned int u = __builtin_bit_cast(unsigned int, f);
    return (unsigned short)((u + 0x7FFFu + ((u >> 16) & 1u)) >> 16);
}

// packed f32->bf16 RNE, 2 elems/inst. No builtin on gfx950 (guide T12) -> asm.
__device__ __forceinline__ unsigned int cvtpk(float lo, float hi) {
    unsigned int r;
    asm("v_cvt_pk_bf16_f32 %0, %1, %2" : "=v"(r) : "v"(lo), "v"(hi));
    return r;
}

#define GLDS16(gp, lp)                                                          \
    __builtin_amdgcn_global_load_lds(                                           \
        (const __attribute__((address_space(1))) void*)(gp),                    \
        (__attribute__((address_space(3))) void*)(lp), 16, 0, 0)

// ---------------------------------------------------------------------------
// GEMM: C[M x N] = A[M x K] * B[N x K]^T, bf16 MFMA, fp32 accumulate.
// GATE=true  (GEMM1): A = x (fp32, reg-stage+cvt), B = W1c (fp32, reg-stage+cvt),
//                     epilogue gates with conv cache and writes bf16 y.
// GATE=false (GEMM2): A = y (bf16, global_load_lds), B = W2 (fp32, reg-stage+cvt),
//                     epilogue writes fp32 out.
// LDS layout: [64 rows][8 slots][8 bf16]; slot s of row r holds k-group s^(r&7).
// ---------------------------------------------------------------------------
template <bool GATE>
__global__ __launch_bounds__(128) void gemm(
    const void* __restrict__ Aptr, const float* __restrict__ Bw,
    const float* __restrict__ cache,      // conv_cache layer 0: [M][N][3]
    const float* __restrict__ convw,      // [N][3]
    unsigned short* __restrict__ Ybf, float* __restrict__ Yout)
{
    __shared__ __align__(16) unsigned short ldsA[2][64 * 64];
    __shared__ __align__(16) unsigned short ldsB[2][64 * 64];

    const int tid  = threadIdx.x;
    const int lane = tid & 63;
    const int w    = tid >> 6;           // wave 0..1
    const int col  = lane & 15;
    const int quad = lane >> 4;
    const int m0   = blockIdx.y * 64;
    const int n0   = blockIdx.x * 64;

    // Coalesced reg-staging coords: base-row rb, k-group cc. Thread covers
    // rows rb+16*jr, 8 floats (32 B) each => per instruction a wave reads
    // 8 consecutive rows x 256 B contiguous.
    const int rb   = (tid >> 3) & 15;    // 0..15
    const int cc   = tid & 7;            // k-group 0..7
    const int slot = cc ^ (rb & 7);      // (rb+16j)&7 == rb&7, thread-constant
    const int wbase = rb * 64 + slot * 8;   // shorts; +jr*1024

    const float* bbase = Bw + (size_t)(n0 + rb) * KDIM + cc * 8;
    const float* abase = nullptr;
    size_t aoff[4] = {};
    if constexpr (GATE) {
        abase = (const float*)Aptr + (size_t)(m0 + rb) * KDIM + cc * 8;
    } else {
        // glds staging: chunk c = rows [8c,8c+8); lane l writes 16B at c*1024+l*16
        // => row 8c+(l>>3), slot l&7 holds k-group (l&7)^(l>>3). Wave w: chunks 4w..4w+3.
        const int rsub = lane >> 3;
        const int kg   = (lane & 7) ^ rsub;
#pragma unroll
        for (int t = 0; t < 4; ++t) {
            const int c = 4 * w + t;
            aoff[t] = (size_t)(m0 + 8 * c + rsub) * KDIM + kg * 8;
        }
    }

    float4 a4[4][2], b4[4][2];

    auto load_tiles = [&](int k0, int buf) {
#pragma unroll
        for (int jr = 0; jr < 4; ++jr) {
            const float* p = bbase + (size_t)(16 * jr) * KDIM + k0;
            b4[jr][0] = *(const float4*)p;
            b4[jr][1] = *(const float4*)(p + 4);
        }
        if constexpr (GATE) {
#pragma unroll
            for (int jr = 0; jr < 4; ++jr) {
                const float* p = abase + (size_t)(16 * jr) * KDIM + k0;
                a4[jr][0] = *(const float4*)p;
                a4[jr][1] = *(const float4*)(p + 4);
            }
        } else {
#pragma unroll
            for (int t = 0; t < 4; ++t)
                GLDS16((const unsigned short*)Aptr + aoff[t] + k0,
                       &ldsA[buf][(4 * w + t) * 512]);
        }
    };

    auto cvt_write = [&](int buf) {
#pragma unroll
        for (int jr = 0; jr < 4; ++jr) {
            uint4 wv;
            wv.x = cvtpk(b4[jr][0].x, b4[jr][0].y);
            wv.y = cvtpk(b4[jr][0].z, b4[jr][0].w);
            wv.z = cvtpk(b4[jr][1].x, b4[jr][1].y);
            wv.w = cvtpk(b4[jr][1].z, b4[jr][1].w);
            *(uint4*)&ldsB[buf][wbase + jr * 1024] = wv;
        }
        if constexpr (GATE) {
#pragma unroll
            for (int jr = 0; jr < 4; ++jr) {
                uint4 wv;
                wv.x = cvtpk(a4[jr][0].x, a4[jr][0].y);
                wv.y = cvtpk(a4[jr][0].z, a4[jr][0].w);
                wv.z = cvtpk(a4[jr][1].x, a4[jr][1].y);
                wv.w = cvtpk(a4[jr][1].z, a4[jr][1].w);
                *(uint4*)&ldsA[buf][wbase + jr * 1024] = wv;
            }
        }
    };

    f32x4 acc[4][2] = {};

    // prologue: stage K-tile 0 into buffer 0
    load_tiles(0, 0);
    cvt_write(0);
    __syncthreads();

    int cur = 0;
    for (int k0 = 0; k0 < KDIM; k0 += 64) {
        const bool more = (k0 + 64 < KDIM);      // block-uniform
        if (more) load_tiles(k0 + 64, cur ^ 1);  // in flight under MFMA below

#pragma unroll
        for (int ks = 0; ks < 2; ++ks) {
            const int rslot = (ks * 4 + quad) ^ (col & 7);
            bf16x8 av[4], bv[2];
#pragma unroll
            for (int i = 0; i < 4; ++i)
                av[i] = *(const bf16x8*)&ldsA[cur][(i * 16 + col) * 64 + rslot * 8];
#pragma unroll
            for (int j = 0; j < 2; ++j)
                bv[j] = *(const bf16x8*)&ldsB[cur][(w * 32 + j * 16 + col) * 64 + rslot * 8];
#pragma unroll
            for (int i = 0; i < 4; ++i)
#pragma unroll
                for (int j = 0; j < 2; ++j)
                    acc[i][j] = __builtin_amdgcn_mfma_f32_16x16x32_bf16(
                        av[i], bv[j], acc[i][j], 0, 0, 0);
        }

        if (more) {
            cvt_write(cur ^ 1);   // compiler inserts vmcnt waits at first use
            __syncthreads();      // writes (incl. glds) visible; old reads done
            cur ^= 1;
        }
    }

    // Epilogue. C/D mapping (HW-verified): row = quad*4 + rr, col = lane&15.
#pragma unroll
    for (int j = 0; j < 2; ++j) {
        const int n = n0 + w * 32 + j * 16 + col;
        float cw0 = 0.f, cw1 = 0.f, cw2 = 0.f;
        if constexpr (GATE) {
            cw0 = convw[n * 3 + 0];
            cw1 = convw[n * 3 + 1];
            cw2 = convw[n * 3 + 2];
        }
#pragma unroll
        for (int i = 0; i < 4; ++i) {
#pragma unroll
            for (int rr = 0; rr < 4; ++rr) {
                const int m = m0 + i * 16 + quad * 4 + rr;
                float v = acc[i][j][rr];
                if constexpr (GATE) {
                    const float* cp = cache + ((size_t)m * NDIM + n) * 3;
                    v *= cp[0] * cw0 + cp[1] * cw1 + cp[2] * cw2;
                    Ybf[(size_t)m * NDIM + n] = bf16rn(v);
                } else {
                    Yout[(size_t)m * NDIM + n] = v;
                }
            }
        }
    }
}

// ---------------------------------------------------------------------------
extern "C" void kernel_launch(void* const* d_in, const int* in_sizes, int n_in,
                              void* d_out, int out_size, void* d_ws, size_t ws_size,
                              hipStream_t stream)
{
    const float* x     = (const float*)d_in[0];
    const float* cache = (const float*)d_in[1];   // layer 0 is at offset 0
    const float* w1    = (const float*)d_in[3];
    const float* w2    = (const float*)d_in[4];
    const float* cw    = (const float*)d_in[5];
    float* out = (float*)d_out;

    unsigned short* yb = (unsigned short*)d_ws;   // 4 MB intermediate (bf16 y)

    dim3 grid(NDIM / 64, MDIM / 64);  // 16 x 32 = 512 blocks, 128 thr each
    gemm<true><<<grid, dim3(128), 0, stream>>>(
        x, w1 + (size_t)NDIM * KDIM,  // W1 rows [D, 2D) = Cg projection
        cache, cw, yb, nullptr);
    gemm<false><<<grid, dim3(128), 0, stream>>>(
        yb, w2, nullptr, nullptr, nullptr, out);
}

// Round 4
// 380.004 us; speedup vs baseline: 1.1024x; 1.0324x over previous
//
#include <hip/hip_runtime.h>

// Lfm2ShortConv decode: out = (Cg ⊙ conv_out) @ W2^T
//   Cg = x @ W1[D:2D]^T          (Bg,xg branches are dead — feed a discarded cache update)
//   conv_out[b,d] = sum_l conv_cache[0,b,d,l] * conv_w[d,0,l]
// M=2048 (batch), N=K=1024. Two bf16-MFMA GEMMs + gate fused in GEMM1 epilogue.
//
// Round 5 (resubmit after broker timeout): timed region = ~362 us harness
// re-poison fills (fixed) + our ~16 us tail. Rounds 1-2 proved in-GEMM
// fp32->bf16 fusion loses to prep_cast + glds (2x operand bytes/step +
// cvt/ds_write serial chain; guide m151 agrees).
// This round: exact round-0 structure (prep_cast + glds staging + swizzled LDS
// + 64x64/2-wave tiles) with the ONE remaining fix — the K-loop was fully
// drained (vmcnt(0) __syncthreads x2) every step, exposing full load latency
// at 1 wave/SIMD. Now: 3 LDS buffers, prefetch depth 2, ONE raw s_barrier per
// step with counted vmcnt(8) (8 glds/tile/wave -> <=8 outstanding == tile t+1
// landed, tile t+2 still in flight). Race-free: step t reads buf[t%3];
// glds(t+2) targets buf[(t-1)%3], whose reads finished at the previous
// barrier's lgkmcnt(0). Barriers 32 -> 16 per block.

#define MDIM 2048
#define NDIM 1024
#define KDIM 1024

typedef __attribute__((ext_vector_type(8))) short bf16x8;
typedef __attribute__((ext_vector_type(4))) float f32x4;

__device__ __forceinline__ unsigned short bf16rn(float f) {
    unsigned int u = __builtin_bit_cast(unsigned int, f);
    return (unsigned short)((u + 0x7FFFu + ((u >> 16) & 1u)) >> 16);
}

#define GLDS16(gp, lp)                                                          \
    __builtin_amdgcn_global_load_lds(                                           \
        (const __attribute__((address_space(1))) void*)(gp),                    \
        (__attribute__((address_space(3))) void*)(lp), 16, 0, 0)

// ---------------------------------------------------------------------------
// Kernel 1: cast x, W1c (=in_proj_w rows [D,2D)), W2 to bf16 (RNE) in d_ws.
// ---------------------------------------------------------------------------
__global__ __launch_bounds__(256) void prep_cast(
    const float* __restrict__ x, const float* __restrict__ w1,
    const float* __restrict__ w2, unsigned short* __restrict__ xb,
    unsigned short* __restrict__ w1b, unsigned short* __restrict__ w2b)
{
    const int t = blockIdx.x * 256 + threadIdx.x;
    const int X4 = MDIM * KDIM / 4;      // 524288
    const int W4 = KDIM * NDIM / 4;      // 262144
    float4 v;
    unsigned short* dst;
    if (t < X4) {
        v = ((const float4*)x)[t];
        dst = xb + (size_t)t * 4;
    } else if (t < X4 + W4) {
        int u = t - X4;
        v = ((const float4*)(w1 + (size_t)NDIM * KDIM))[u];   // rows [D, 2D)
        dst = w1b + (size_t)u * 4;
    } else {
        int u = t - X4 - W4;
        v = ((const float4*)w2)[u];
        dst = w2b + (size_t)u * 4;
    }
    ushort4 o;
    o.x = bf16rn(v.x); o.y = bf16rn(v.y); o.z = bf16rn(v.z); o.w = bf16rn(v.w);
    *(ushort4*)dst = o;
}

// ---------------------------------------------------------------------------
// GEMM: C[M x N] = A[M x K] * B[N x K]^T, bf16 inputs, fp32 accumulate.
// Block = 64x64 tile, 2 waves; wave w handles n-half w (64x32 subtile).
// LDS layout: [64 rows][8 slots][8 elems]; slot s of row r holds k-group
// s ^ (r&7) — matches glds lane->base+lane*16 placement with per-lane source
// addresses; every fragment ds_read_b128 is conflict-free.
// ---------------------------------------------------------------------------
template <bool GATE>
__global__ __launch_bounds__(128) void gemm(
    const unsigned short* __restrict__ A, const unsigned short* __restrict__ Bm,
    const float* __restrict__ cache,      // conv_cache layer 0: [M][N][3]
    const float* __restrict__ convw,      // [N][3]
    unsigned short* __restrict__ Ybf, float* __restrict__ Yout)
{
    __shared__ __align__(16) unsigned short ldsA[3][64 * 64];   // 24 KB
    __shared__ __align__(16) unsigned short ldsB[3][64 * 64];   // 24 KB

    const int tid  = threadIdx.x;
    const int lane = tid & 63;
    const int w    = tid >> 6;           // wave 0..1
    const int col  = lane & 15;
    const int quad = lane >> 4;
    const int m0   = blockIdx.y * 64;
    const int n0   = blockIdx.x * 64;

    // Staging: chunk c (1 KiB) = rows [8c, 8c+8). Lane l writes 16 B at
    // c*1024 + l*16 => row 8c + (l>>3), slot l&7, which must hold k-group
    // (l&7) ^ ((l>>3)&7). Wave w stages chunks 4w..4w+3 of A and B.
    const int rsub = lane >> 3;
    const int kg   = (lane & 7) ^ rsub;
    size_t aoff[4], boff[4];
#pragma unroll
    for (int t = 0; t < 4; ++t) {
        const int c = 4 * w + t;
        aoff[t] = (size_t)(m0 + 8 * c + rsub) * KDIM + kg * 8;
        boff[t] = (size_t)(n0 + 8 * c + rsub) * KDIM + kg * 8;
    }

    // Per wave: 8 glds (4 A + 4 B) per K-tile => vmcnt(8) == "newest tile may
    // be outstanding, everything older has landed".
    auto stage = [&](int tt, int buf) {
#pragma unroll
        for (int t = 0; t < 4; ++t) {
            const int c = 4 * w + t;
            GLDS16(A  + aoff[t] + tt * 64, &ldsA[buf][c * 512]);
            GLDS16(Bm + boff[t] + tt * 64, &ldsB[buf][c * 512]);
        }
    };

    f32x4 acc[4][2] = {};

    // prologue: tiles 0,1 in flight; wait oldest 8 (tile 0) only.
    stage(0, 0);
    stage(1, 1);
    asm volatile("s_waitcnt vmcnt(8)" ::: "memory");
    __builtin_amdgcn_s_barrier();
    __builtin_amdgcn_sched_barrier(0);

    int cur = 0;
    for (int t = 0; t < 16; ++t) {
        if (t < 14) stage(t + 2, (t + 2) % 3);

#pragma unroll
        for (int ks = 0; ks < 2; ++ks) {
            const int slot = (ks * 4 + quad) ^ (col & 7);
            bf16x8 av[4], bv[2];
#pragma unroll
            for (int i = 0; i < 4; ++i)
                av[i] = *(const bf16x8*)&ldsA[cur][(i * 16 + col) * 64 + slot * 8];
#pragma unroll
            for (int j = 0; j < 2; ++j)
                bv[j] = *(const bf16x8*)&ldsB[cur][(w * 32 + j * 16 + col) * 64 + slot * 8];
#pragma unroll
            for (int i = 0; i < 4; ++i)
#pragma unroll
                for (int j = 0; j < 2; ++j)
                    acc[i][j] = __builtin_amdgcn_mfma_f32_16x16x32_bf16(
                        av[i], bv[j], acc[i][j], 0, 0, 0);
        }

        if (t < 15) {
            // tile t+1 must have landed; tile t+2 (if any) stays in flight.
            if (t < 14)
                asm volatile("s_waitcnt vmcnt(8) lgkmcnt(0)" ::: "memory");
            else
                asm volatile("s_waitcnt vmcnt(0) lgkmcnt(0)" ::: "memory");
            __builtin_amdgcn_s_barrier();
            __builtin_amdgcn_sched_barrier(0);
        }
        cur = (cur == 2) ? 0 : cur + 1;
    }

    // Epilogue. C/D mapping (HW-verified): row = quad*4 + rr, col = lane&15.
#pragma unroll
    for (int j = 0; j < 2; ++j) {
        const int n = n0 + w * 32 + j * 16 + col;
        float cw0 = 0.f, cw1 = 0.f, cw2 = 0.f;
        if (GATE) {
            cw0 = convw[n * 3 + 0];
            cw1 = convw[n * 3 + 1];
            cw2 = convw[n * 3 + 2];
        }
#pragma unroll
        for (int i = 0; i < 4; ++i) {
#pragma unroll
            for (int rr = 0; rr < 4; ++rr) {
                const int m = m0 + i * 16 + quad * 4 + rr;
                float v = acc[i][j][rr];
                if (GATE) {
                    const float* cp = cache + ((size_t)m * NDIM + n) * 3;
                    v *= cp[0] * cw0 + cp[1] * cw1 + cp[2] * cw2;
                    Ybf[(size_t)m * NDIM + n] = bf16rn(v);
                } else {
                    Yout[(size_t)m * NDIM + n] = v;
                }
            }
        }
    }
}

// ---------------------------------------------------------------------------
extern "C" void kernel_launch(void* const* d_in, const int* in_sizes, int n_in,
                              void* d_out, int out_size, void* d_ws, size_t ws_size,
                              hipStream_t stream)
{
    const float* x     = (const float*)d_in[0];
    const float* cache = (const float*)d_in[1];   // layer 0 is at offset 0
    const float* w1    = (const float*)d_in[3];
    const float* w2    = (const float*)d_in[4];
    const float* cw    = (const float*)d_in[5];
    float* out = (float*)d_out;

    unsigned short* xb  = (unsigned short*)d_ws;            // 4 MB
    unsigned short* w1b = xb  + (size_t)MDIM * KDIM;        // 2 MB
    unsigned short* w2b = w1b + (size_t)KDIM * NDIM;        // 2 MB
    unsigned short* yb  = w2b + (size_t)KDIM * NDIM;        // 4 MB (12 MB total)

    prep_cast<<<dim3(4096), dim3(256), 0, stream>>>(x, w1, w2, xb, w1b, w2b);

    dim3 grid(NDIM / 64, MDIM / 64);  // 16 x 32 = 512 blocks, 128 thr each
    gemm<true><<<grid, dim3(128), 0, stream>>>(xb, w1b, cache, cw, yb, nullptr);
    gemm<false><<<grid, dim3(128), 0, stream>>>(yb, w2b, nullptr, nullptr, nullptr, out);
}